// Round 1
// baseline (222.045 us; speedup 1.0000x reference)
//
#include <hip/hip_runtime.h>
#include <math.h>

#define BB 32
#define TT 4096
#define FF 256
#define K_TOP 409          // int(4096 * 0.1)
#define EMPH 1.5f

// ---------------------------------------------------------------------------
// K0: zero the output (d_out is poisoned to 0xAA before every timed launch)
// ---------------------------------------------------------------------------
__global__ void zero_kernel(float* __restrict__ p, int n) {
    int i = blockIdx.x * 256 + threadIdx.x;
    if (i < n) p[i] = 0.f;
}

// ---------------------------------------------------------------------------
// K1: e[b*T+t] = tanh(dot(x[b,t,:], W) + bias)
// one wave (64 lanes) per timestep, float4 per lane covers F=256.
// grid = B*T/4 blocks of 256 threads (4 waves).
// ---------------------------------------------------------------------------
__global__ __launch_bounds__(256) void dot_tanh_kernel(const float* __restrict__ x,
                                                       const float* __restrict__ W,
                                                       const float* __restrict__ bias,
                                                       float* __restrict__ e) {
    const int wave = threadIdx.x >> 6;
    const int lane = threadIdx.x & 63;
    const size_t bt = (size_t)blockIdx.x * 4 + wave;   // global timestep index (b*T+t)

    const float4* xv = (const float4*)(x + bt * FF);
    const float4* wv = (const float4*)W;
    const float4 xe = xv[lane];
    const float4 we = wv[lane];
    float d = xe.x * we.x + xe.y * we.y + xe.z * we.z + xe.w * we.w;

    #pragma unroll
    for (int off = 32; off; off >>= 1) d += __shfl_down(d, off);

    if (lane == 0) e[bt] = tanhf(d + bias[0]);
}

// ---------------------------------------------------------------------------
// K2: per-batch softmax over T + radix-select of the K_TOP-th largest score +
//     write final per-timestep weight w[b,t] = softmax * (top-k ? 1.5 : 1.0).
// One block (256 threads) per batch; 16 elements per thread in registers.
// ---------------------------------------------------------------------------
__global__ __launch_bounds__(256) void softmax_select_kernel(const float* __restrict__ e,
                                                             float* __restrict__ w) {
    const int b = blockIdx.x;
    const int tid = threadIdx.x;
    const int wave = tid >> 6, lane = tid & 63;
    const float* eb = e + (size_t)b * TT;

    float ev[16];
    unsigned key[16];
    float lmax = -1e30f;
    #pragma unroll
    for (int j = 0; j < 16; j++) {
        float v = eb[tid + 256 * j];
        ev[j] = v;
        unsigned u = __float_as_uint(v);
        // order-preserving flip: larger key <=> larger float
        key[j] = (u & 0x80000000u) ? ~u : (u | 0x80000000u);
        lmax = fmaxf(lmax, v);
    }

    __shared__ float sf[4];
    __shared__ int   sc[4];

    // block max
    #pragma unroll
    for (int off = 32; off; off >>= 1) lmax = fmaxf(lmax, __shfl_down(lmax, off));
    if (lane == 0) sf[wave] = lmax;
    __syncthreads();
    const float emax = fmaxf(fmaxf(sf[0], sf[1]), fmaxf(sf[2], sf[3]));
    __syncthreads();

    // block sum of exp
    float pe[16];
    float lsum = 0.f;
    #pragma unroll
    for (int j = 0; j < 16; j++) { pe[j] = expf(ev[j] - emax); lsum += pe[j]; }
    #pragma unroll
    for (int off = 32; off; off >>= 1) lsum += __shfl_down(lsum, off);
    if (lane == 0) sf[wave] = lsum;
    __syncthreads();
    const float sumexp = sf[0] + sf[1] + sf[2] + sf[3];

    // MSB-first radix select: key of the K_TOP-th largest element
    unsigned prefix = 0u, mask = 0u;
    int kk = K_TOP;
    for (int bit = 31; bit >= 0; bit--) {
        const unsigned bm = 1u << bit;
        const unsigned m2 = mask | bm;
        const unsigned want = prefix | bm;
        int c = 0;
        #pragma unroll
        for (int j = 0; j < 16; j++) c += (int)((key[j] & m2) == want);
        #pragma unroll
        for (int off = 32; off; off >>= 1) c += __shfl_down(c, off);
        __syncthreads();                 // protect sc reads of previous iter
        if (lane == 0) sc[wave] = c;
        __syncthreads();
        const int tot = sc[0] + sc[1] + sc[2] + sc[3];
        if (tot >= kk) prefix = want; else kk -= tot;
        mask = m2;
    }
    const unsigned Kkey = prefix;

    const float inv = 1.f / sumexp;
    float* wb = w + (size_t)b * TT;
    #pragma unroll
    for (int j = 0; j < 16; j++) {
        float val = pe[j] * inv;
        if (key[j] >= Kkey) val *= EMPH;
        wb[tid + 256 * j] = val;
    }
}

// ---------------------------------------------------------------------------
// K3: out[b,f] += sum_t x[b,t,f] * w[b,t]   (atomicAdd over T-chunks)
// grid = B * (T/CHUNK) blocks of 256; one wave per timestep, float4 per lane.
// ---------------------------------------------------------------------------
#define CHUNK 128
__global__ __launch_bounds__(256) void wsum_kernel(const float* __restrict__ x,
                                                   const float* __restrict__ w,
                                                   float* __restrict__ out) {
    const int chunks = TT / CHUNK;                  // 32
    const int b  = blockIdx.x / chunks;
    const int c0 = (blockIdx.x % chunks) * CHUNK;
    const int wave = threadIdx.x >> 6, lane = threadIdx.x & 63;

    const float4* xb = (const float4*)(x + ((size_t)b * TT + c0) * FF);
    const float*  wb = w + (size_t)b * TT + c0;

    float4 acc = make_float4(0.f, 0.f, 0.f, 0.f);
    for (int t = wave; t < CHUNK; t += 4) {
        const float  wt = wb[t];                    // broadcast within wave
        const float4 xe = xb[t * 64 + lane];
        acc.x += xe.x * wt; acc.y += xe.y * wt;
        acc.z += xe.z * wt; acc.w += xe.w * wt;
    }

    __shared__ float4 part4[4][64];
    part4[wave][lane] = acc;
    __syncthreads();

    const float* pf = (const float*)part4;          // viewed as [4][256]
    const float s = pf[threadIdx.x] + pf[256 + threadIdx.x] +
                    pf[512 + threadIdx.x] + pf[768 + threadIdx.x];
    atomicAdd(&out[b * FF + threadIdx.x], s);
}

// ---------------------------------------------------------------------------
extern "C" void kernel_launch(void* const* d_in, const int* in_sizes, int n_in,
                              void* d_out, int out_size, void* d_ws, size_t ws_size,
                              hipStream_t stream) {
    const float* x    = (const float*)d_in[0];   // [B,T,F]
    const float* W    = (const float*)d_in[1];   // [F,1]
    const float* bias = (const float*)d_in[2];   // [1]
    float* out = (float*)d_out;                  // [B,1,F]

    float* e = (float*)d_ws;                     // B*T floats
    float* w = e + (size_t)BB * TT;              // B*T floats

    zero_kernel<<<(BB * FF + 255) / 256, 256, 0, stream>>>(out, BB * FF);
    dot_tanh_kernel<<<BB * TT / 4, 256, 0, stream>>>(x, W, bias, e);
    softmax_select_kernel<<<BB, 256, 0, stream>>>(e, w);
    wsum_kernel<<<BB * (TT / CHUNK), 256, 0, stream>>>(x, w, out);
}

// Round 2
// 217.925 us; speedup vs baseline: 1.0189x; 1.0189x over previous
//
#include <hip/hip_runtime.h>
#include <math.h>

#define BB 32
#define TT 4096
#define FF 256
#define CH 64              // timesteps per K1 block
#define NC (TT / CH)       // 64 chunks per batch
#define ST 16              // sub-tile timesteps (4 rows per wave)
#define K_TOP 409          // int(4096 * 0.1)
#define NSEG 16            // K3 segments per batch (256 timesteps each)
#define SEGT (TT / NSEG)   // 256
#define CPS (NC / NSEG)    // 4 chunks per segment

__device__ __forceinline__ unsigned flip_key(float v) {
    unsigned u = __float_as_uint(v);
    return (u & 0x80000000u) ? ~u : (u | 0x80000000u);
}

// ---------------------------------------------------------------------------
// K0: zero the output (poisoned to 0xAA before every timed launch)
// ---------------------------------------------------------------------------
__global__ void zero_kernel(float* __restrict__ p, int n) {
    int i = blockIdx.x * 256 + threadIdx.x;
    if (i < n) p[i] = 0.f;
}

// ---------------------------------------------------------------------------
// K1: fused scores + online-softmax chunk partials. ONE HBM pass over x.
// grid = B*NC blocks of 256 (4 waves). Wave w owns rows {s0+4w..s0+4w+3} of
// each 16-row sub-tile: loads them once (registers), dots via butterfly,
// then reuses the SAME registers for the exp-weighted accumulation.
// Outputs: e[B*T], P[B*NC*F] (= sum_t exp(e-m_c) x), cm[B*NC], cs[B*NC].
// ---------------------------------------------------------------------------
__global__ __launch_bounds__(256) void fused_pass1(const float* __restrict__ x,
                                                   const float* __restrict__ W,
                                                   const float* __restrict__ bias,
                                                   float* __restrict__ e,
                                                   float* __restrict__ P,
                                                   float* __restrict__ cm,
                                                   float* __restrict__ cs) {
    const int b = blockIdx.x / NC;
    const int c = blockIdx.x % NC;
    const int tid = threadIdx.x;
    const int wv = tid >> 6, ln = tid & 63;

    const float* xc = x + ((size_t)b * TT + (size_t)c * CH) * FF;
    const float4 wvec = ((const float4*)W)[ln];
    const float  bb   = bias[0];

    __shared__ float se[ST];
    __shared__ float4 part4[4][64];
    __shared__ float swsum[4];

    float4 acc = make_float4(0.f, 0.f, 0.f, 0.f);
    float  m = -1e30f, ssum = 0.f;

    for (int s0 = 0; s0 < CH; s0 += ST) {
        // ---- phase 1: this wave's 4 rows -> registers + scores ----
        float4 xr[4];
        #pragma unroll
        for (int i = 0; i < 4; i++) {
            const int tl = s0 + wv * 4 + i;
            xr[i] = ((const float4*)(xc + (size_t)tl * FF))[ln];
        }
        float dv[4];
        #pragma unroll
        for (int i = 0; i < 4; i++)
            dv[i] = xr[i].x * wvec.x + xr[i].y * wvec.y +
                    xr[i].z * wvec.z + xr[i].w * wvec.w;
        #pragma unroll
        for (int i = 0; i < 4; i++) {
            float d = dv[i];
            #pragma unroll
            for (int off = 32; off; off >>= 1) d += __shfl_xor(d, off);
            dv[i] = tanhf(d + bb);   // all lanes hold the value (no divergence)
        }
        __syncthreads();             // previous sub-tile's se readers are done
        if (ln == 0) {
            #pragma unroll
            for (int i = 0; i < 4; i++) {
                se[wv * 4 + i] = dv[i];
                e[(size_t)b * TT + c * CH + s0 + wv * 4 + i] = dv[i];
            }
        }
        __syncthreads();

        // ---- phase 2: online-softmax update using registers ----
        float lm = m;
        #pragma unroll
        for (int i = 0; i < ST; i++) lm = fmaxf(lm, se[i]);
        const float alpha = __expf(m - lm);
        acc.x *= alpha; acc.y *= alpha; acc.z *= alpha; acc.w *= alpha;
        ssum *= alpha;
        #pragma unroll
        for (int i = 0; i < 4; i++) {
            const float wgt = __expf(dv[i] - lm);
            ssum += wgt;
            acc.x += wgt * xr[i].x; acc.y += wgt * xr[i].y;
            acc.z += wgt * xr[i].z; acc.w += wgt * xr[i].w;
        }
        m = lm;
    }

    // ---- combine the 4 per-wave partials -> P[b,c,:] ----
    part4[wv][ln] = acc;
    if (ln == 0) swsum[wv] = ssum;
    __syncthreads();
    const float* pf = (const float*)part4;   // [4][256] floats
    const float p = pf[tid] + pf[256 + tid] + pf[512 + tid] + pf[768 + tid];
    P[((size_t)b * NC + c) * FF + tid] = p;
    if (tid == 0) {
        cm[b * NC + c] = m;
        cs[b * NC + c] = swsum[0] + swsum[1] + swsum[2] + swsum[3];
    }
}

// ---------------------------------------------------------------------------
// K2: per-batch stats. gmax/Z from chunk (m,s); radix-select the K_TOP-th
// largest score key. One block per batch. stats[b] = {gmax, Z, Kkey}.
// ---------------------------------------------------------------------------
__global__ __launch_bounds__(256) void select_kernel(const float* __restrict__ e,
                                                     const float* __restrict__ cm,
                                                     const float* __restrict__ cs,
                                                     float* __restrict__ stats) {
    const int b = blockIdx.x;
    const int tid = threadIdx.x;
    const int wv = tid >> 6, ln = tid & 63;

    __shared__ float sgm, sZ;
    __shared__ int sc[4];

    if (tid < 64) {                       // wave 0: gmax and Z over NC=64 chunks
        const float mm = cm[b * NC + tid];
        const float ss = cs[b * NC + tid];
        float g = mm;
        #pragma unroll
        for (int off = 32; off; off >>= 1) g = fmaxf(g, __shfl_xor(g, off));
        float zz = ss * __expf(mm - g);
        #pragma unroll
        for (int off = 32; off; off >>= 1) zz += __shfl_xor(zz, off);
        if (tid == 0) { sgm = g; sZ = zz; }
    }

    const float* eb = e + (size_t)b * TT;
    unsigned key[16];
    #pragma unroll
    for (int j = 0; j < 16; j++) key[j] = flip_key(eb[tid + 256 * j]);

    // MSB-first radix select for the K_TOP-th largest key
    unsigned prefix = 0u, mask = 0u;
    int kk = K_TOP;
    for (int bit = 31; bit >= 0; bit--) {
        const unsigned bm = 1u << bit;
        const unsigned m2 = mask | bm;
        const unsigned want = prefix | bm;
        int cnt = 0;
        #pragma unroll
        for (int j = 0; j < 16; j++) cnt += (int)((key[j] & m2) == want);
        #pragma unroll
        for (int off = 32; off; off >>= 1) cnt += __shfl_down(cnt, off);
        __syncthreads();
        if (ln == 0) sc[wv] = cnt;
        __syncthreads();
        const int tot = sc[0] + sc[1] + sc[2] + sc[3];
        if (tot >= kk) prefix = want; else kk -= tot;
        mask = m2;
    }

    if (tid == 0) {
        stats[3 * b + 0] = sgm;
        stats[3 * b + 1] = sZ;
        stats[3 * b + 2] = __uint_as_float(prefix);
    }
}

// ---------------------------------------------------------------------------
// K3: combine chunk partials + top-k emphasis gather.
// grid = B*NSEG blocks of 256; block (b,s) handles chunks 4s..4s+3 and
// timesteps [s*256, s*256+256). Thread tid owns feature tid.
// out[b,f] += ( sum_c P*e^{m_c-gmax} + 0.5*sum_{topk t} e^{e_t-gmax} x ) / Z
// ---------------------------------------------------------------------------
__global__ __launch_bounds__(256) void combine_kernel(const float* __restrict__ x,
                                                      const float* __restrict__ e,
                                                      const float* __restrict__ P,
                                                      const float* __restrict__ cm,
                                                      const float* __restrict__ stats,
                                                      float* __restrict__ out) {
    const int b = blockIdx.x / NSEG;
    const int s = blockIdx.x % NSEG;
    const int tid = threadIdx.x;

    const float gmax = stats[3 * b + 0];
    const float Z    = stats[3 * b + 1];
    const unsigned Kkey = __float_as_uint(stats[3 * b + 2]);

    float acc = 0.f;
    #pragma unroll
    for (int c = 0; c < CPS; c++) {
        const int cc = s * CPS + c;
        const float sc2 = __expf(cm[b * NC + cc] - gmax);
        acc += P[((size_t)b * NC + cc) * FF + tid] * sc2;
    }

    __shared__ int scount;
    __shared__ int slist[SEGT];
    __shared__ float sval[SEGT];
    if (tid == 0) scount = 0;
    __syncthreads();

    const int t = s * SEGT + tid;
    const float ev = e[(size_t)b * TT + t];
    if (flip_key(ev) >= Kkey) {
        const int i = atomicAdd(&scount, 1);
        slist[i] = t;
        sval[i] = ev;
    }
    __syncthreads();

    const int n = scount;
    for (int i = 0; i < n; i++) {
        const float coeff = 0.5f * __expf(sval[i] - gmax);
        acc += coeff * x[((size_t)b * TT + slist[i]) * FF + tid];
    }

    atomicAdd(&out[b * FF + tid], acc / Z);
}

// ---------------------------------------------------------------------------
extern "C" void kernel_launch(void* const* d_in, const int* in_sizes, int n_in,
                              void* d_out, int out_size, void* d_ws, size_t ws_size,
                              hipStream_t stream) {
    const float* x    = (const float*)d_in[0];   // [B,T,F]
    const float* W    = (const float*)d_in[1];   // [F,1]
    const float* bias = (const float*)d_in[2];   // [1]
    float* out = (float*)d_out;                  // [B,1,F]

    float* e     = (float*)d_ws;                 // B*T
    float* P     = e + (size_t)BB * TT;          // B*NC*F
    float* cm    = P + (size_t)BB * NC * FF;     // B*NC
    float* cs    = cm + BB * NC;                 // B*NC
    float* stats = cs + BB * NC;                 // 3*B

    zero_kernel<<<(BB * FF + 255) / 256, 256, 0, stream>>>(out, BB * FF);
    fused_pass1<<<BB * NC, 256, 0, stream>>>(x, W, bias, e, P, cm, cs);
    select_kernel<<<BB, 256, 0, stream>>>(e, cm, cs, stats);
    combine_kernel<<<BB * NSEG, 256, 0, stream>>>(x, e, P, cm, stats, out);
}